// Round 2
// baseline (1381.299 us; speedup 1.0000x reference)
//
#include <hip/hip_runtime.h>
#include <cstdint>
#include <cstddef>

typedef __bf16 bf16_t;
typedef __bf16 bf16x8 __attribute__((ext_vector_type(8)));
typedef float floatx4 __attribute__((ext_vector_type(4)));

static constexpr int T_TOK = 4096;
static constexpr int HDIM  = 2048;
static constexpr int DDIM  = 1024;
static constexpr int ESH   = 2;
static constexpr int ERT   = 16;
static constexpr int NPAIR = 2 * T_TOK;         // 8192
static constexpr int NPAIR_PAD = NPAIR + 128;   // pad so tile over-reads stay in-bounds

__device__ __forceinline__ float gelu_f(float v) {
  return 0.5f * v * (1.0f + erff(v * 0.70710678118654752440f));
}

// ---------------- router: logits -> softmax -> top2, atomic counts ----------------
__global__ __launch_bounds__(256) void router_kernel(
    const float* __restrict__ x, const float* __restrict__ Wr,
    int* __restrict__ top_e, float* __restrict__ top_w, int* __restrict__ counts)
{
  const int t = blockIdx.x;
  const int tid = threadIdx.x;
  float acc[ERT];
#pragma unroll
  for (int e = 0; e < ERT; ++e) acc[e] = 0.f;
  const float* xr = x + (long)t * HDIM;
  for (int h = tid; h < HDIM; h += 256) {
    const float xv = xr[h];
    const float4* w4 = (const float4*)(Wr + h * ERT);
    const float4 w0 = w4[0], w1 = w4[1], w2 = w4[2], w3 = w4[3];
    acc[0]  += xv * w0.x; acc[1]  += xv * w0.y; acc[2]  += xv * w0.z; acc[3]  += xv * w0.w;
    acc[4]  += xv * w1.x; acc[5]  += xv * w1.y; acc[6]  += xv * w1.z; acc[7]  += xv * w1.w;
    acc[8]  += xv * w2.x; acc[9]  += xv * w2.y; acc[10] += xv * w2.z; acc[11] += xv * w2.w;
    acc[12] += xv * w3.x; acc[13] += xv * w3.y; acc[14] += xv * w3.z; acc[15] += xv * w3.w;
  }
  __shared__ float s[256][ERT + 1];
#pragma unroll
  for (int e = 0; e < ERT; ++e) s[tid][e] = acc[e];
  __syncthreads();
  for (int st = 128; st >= 1; st >>= 1) {
    if (tid < st) {
#pragma unroll
      for (int e = 0; e < ERT; ++e) s[tid][e] += s[tid + st][e];
    }
    __syncthreads();
  }
  if (tid == 0) {
    float l[ERT];
    float mx = -1e30f;
#pragma unroll
    for (int e = 0; e < ERT; ++e) { l[e] = s[0][e]; mx = fmaxf(mx, l[e]); }
    float sum = 0.f;
#pragma unroll
    for (int e = 0; e < ERT; ++e) { l[e] = expf(l[e] - mx); sum += l[e]; }
    const float inv = 1.f / sum;
    float v0 = -1.f, v1 = -1.f; int i0 = 0, i1 = 0;
#pragma unroll
    for (int e = 0; e < ERT; ++e) {
      const float p = l[e] * inv;
      if (p > v0) { v1 = v0; i1 = i0; v0 = p; i0 = e; }
      else if (p > v1) { v1 = p; i1 = e; }
    }
    top_e[2 * t] = i0; top_e[2 * t + 1] = i1;
    top_w[2 * t] = v0; top_w[2 * t + 1] = v1;
    atomicAdd(&counts[i0], 1); atomicAdd(&counts[i1], 1);
  }
}

// ---------------- tiny prefix sum over 16 experts ----------------
__global__ void prefix_kernel(const int* __restrict__ counts, int* __restrict__ offsets) {
  if (threadIdx.x == 0) {
    int s = 0;
    for (int e = 0; e < ERT; ++e) { offsets[e] = s; s += counts[e]; }
    offsets[ERT] = s;
  }
}

// ---------------- scatter tokens into per-expert contiguous slots ----------------
__global__ __launch_bounds__(256) void scatter_kernel(
    const int* __restrict__ top_e, const float* __restrict__ top_w,
    const int* __restrict__ offsets, int* __restrict__ cursor,
    int* __restrict__ pair_token, float* __restrict__ pair_w)
{
  const int t = blockIdx.x * 256 + threadIdx.x;
  if (t >= T_TOK) return;
#pragma unroll
  for (int k = 0; k < 2; ++k) {
    const int e = top_e[2 * t + k];
    const int pos = atomicAdd(&cursor[e], 1);
    const int slot = offsets[e] + pos;
    pair_token[slot] = t;
    pair_w[slot] = top_w[2 * t + k];
  }
}

// ---------------- x fp32 -> bf16 ----------------
__global__ __launch_bounds__(256) void cast_x_kernel(const float* __restrict__ x, bf16_t* __restrict__ xb) {
  const long base = (long)blockIdx.x * HDIM + threadIdx.x * 8;
  const float4 a = *(const float4*)(x + base);
  const float4 b = *(const float4*)(x + base + 4);
  bf16x8 v;
  v[0] = (__bf16)a.x; v[1] = (__bf16)a.y; v[2] = (__bf16)a.z; v[3] = (__bf16)a.w;
  v[4] = (__bf16)b.x; v[5] = (__bf16)b.y; v[6] = (__bf16)b.z; v[7] = (__bf16)b.w;
  *(bf16x8*)(xb + base) = v;
}

// ---------------- gather routed rows (fp32 -> bf16) ----------------
__global__ __launch_bounds__(256) void gather_kernel(
    const float* __restrict__ x, const int* __restrict__ pair_token, bf16_t* __restrict__ xg)
{
  const int slot = blockIdx.x;
  const int tok = pair_token[slot];
  const float* src = x + (long)tok * HDIM;
  const int c = threadIdx.x * 8;
  const float4 a = *(const float4*)(src + c);
  const float4 b = *(const float4*)(src + c + 4);
  bf16x8 v;
  v[0] = (__bf16)a.x; v[1] = (__bf16)a.y; v[2] = (__bf16)a.z; v[3] = (__bf16)a.w;
  v[4] = (__bf16)b.x; v[5] = (__bf16)b.y; v[6] = (__bf16)b.z; v[7] = (__bf16)b.w;
  *(bf16x8*)(xg + (long)slot * HDIM + c) = v;
}

// ---------------- transpose + cast: in fp32 [R][C] -> out bf16 [C][R], per mat ----------------
__global__ __launch_bounds__(256) void transpose_cast_kernel(
    const float* __restrict__ in, bf16_t* __restrict__ out, int R, int C)
{
  __shared__ float tl[64][65];
  const long mat = blockIdx.z;
  in  += mat * (long)R * C;
  out += mat * (long)R * C;
  const int c0 = blockIdx.x * 64, r0 = blockIdx.y * 64;
  const int tid = threadIdx.x;
  const int lr = tid >> 4;          // 0..15
  const int lc4 = (tid & 15) * 4;   // 0,4,...,60
#pragma unroll
  for (int i = 0; i < 4; ++i) {
    const int r = lr + i * 16;
    const float4 v = *(const float4*)(in + (long)(r0 + r) * C + c0 + lc4);
    tl[r][lc4 + 0] = v.x; tl[r][lc4 + 1] = v.y; tl[r][lc4 + 2] = v.z; tl[r][lc4 + 3] = v.w;
  }
  __syncthreads();
#pragma unroll
  for (int i = 0; i < 4; ++i) {
    const int c = lr + i * 16;
    ushort4 o;
    o.x = __builtin_bit_cast(unsigned short, (__bf16)tl[lc4 + 0][c]);
    o.y = __builtin_bit_cast(unsigned short, (__bf16)tl[lc4 + 1][c]);
    o.z = __builtin_bit_cast(unsigned short, (__bf16)tl[lc4 + 2][c]);
    o.w = __builtin_bit_cast(unsigned short, (__bf16)tl[lc4 + 3][c]);
    *(ushort4*)((unsigned short*)out + (long)(c0 + c) * R + r0 + lc4) = o;
  }
}

// ---------------- 128x128 MFMA GEMM, BK=64, A:[M][K] bf16, B:[N][K] bf16 (both k-contiguous) --------
// MODE 0: shared-up   C = gelu(A@B^T) -> midsh bf16   (grid 32 x 16)
// MODE 1: shared-down C = A@B^T -> out fp32, B k-segmented per expert (grid 32 x 16)
// MODE 2: routed-up   C = gelu(A@B^T)*w -> midrt bf16, grouped (grid 32 x 8 x 16)
// MODE 3: routed-down atomicAdd(out[token], A@B^T), grouped (grid 32 x 16 x 16)
template<int MODE>
__global__ __launch_bounds__(256) void gemm_kernel(
    const bf16_t* __restrict__ Abase, const bf16_t* __restrict__ Bbase,
    bf16_t* __restrict__ Cbf, float* __restrict__ Cf,
    const int* __restrict__ counts, const int* __restrict__ offsets,
    const float* __restrict__ pair_w, const int* __restrict__ pair_token)
{
  constexpr int K   = (MODE == 3) ? 1024 : 2048;
  constexpr int LDA = (MODE == 3) ? 1024 : 2048;
  constexpr int LDB = (MODE == 1 || MODE == 3) ? 1024 : 2048;

  const int mt = blockIdx.x, nt = blockIdx.y, e = blockIdx.z;
  const int m0 = mt * 128;
  int cnt = 0, segoff = 0;
  if (MODE == 2 || MODE == 3) {
    cnt = counts[e];
    if (m0 >= cnt) return;
    segoff = offsets[e];
  }

  const bf16_t* Ab;
  const bf16_t* Bb;
  if (MODE == 0) {
    Ab = Abase + (long)m0 * LDA;
    Bb = Bbase + (long)(nt >> 3) * ((long)DDIM * HDIM) + (long)((nt & 7) * 128) * LDB;
  } else if (MODE == 1) {
    Ab = Abase + (long)m0 * LDA;
    Bb = Bbase + (long)(nt * 128) * LDB;
  } else if (MODE == 2) {
    Ab = Abase + (long)(segoff + m0) * LDA;
    Bb = Bbase + (long)e * ((long)DDIM * HDIM) + (long)(nt * 128) * LDB;
  } else {
    Ab = Abase + (long)(segoff + m0) * LDA;
    Bb = Bbase + (long)e * ((long)HDIM * DDIM) + (long)(nt * 128) * LDB;
  }

  __shared__ bf16_t As[128 * 72];   // [m][k], row stride 72 (=9*16B, 16B aligned, conflict-light)
  __shared__ bf16_t Bs[128 * 72];   // [n][k]

  const int tid = threadIdx.x;
  const int rr = tid >> 3, ch = tid & 7;       // staging: row, 16B chunk
  const int lane = tid & 63, wv = tid >> 6;
  const int ln = lane & 15, quad = lane >> 4;
  const int wm = (wv & 1) * 64, wn = (wv >> 1) * 64;

  floatx4 acc[4][4];
#pragma unroll
  for (int i = 0; i < 4; ++i)
#pragma unroll
    for (int j = 0; j < 4; ++j) acc[i][j] = (floatx4){0.f, 0.f, 0.f, 0.f};

  for (int k0 = 0; k0 < K; k0 += 64) {
    bf16x8 av[4], bv[4];
    long bkoff;
    if (MODE == 1) bkoff = (long)(k0 >> 10) * ((long)HDIM * DDIM) + (k0 & 1023);
    else bkoff = k0;
#pragma unroll
    for (int i = 0; i < 4; ++i) {
      av[i] = *(const bf16x8*)(Ab + (long)(rr + i * 32) * LDA + k0 + ch * 8);
      bv[i] = *(const bf16x8*)(Bb + (long)(rr + i * 32) * LDB + bkoff + ch * 8);
    }
    __syncthreads();
#pragma unroll
    for (int i = 0; i < 4; ++i) {
      *(bf16x8*)(&As[(rr + i * 32) * 72 + ch * 8]) = av[i];
      *(bf16x8*)(&Bs[(rr + i * 32) * 72 + ch * 8]) = bv[i];
    }
    __syncthreads();
#pragma unroll
    for (int s = 0; s < 2; ++s) {
      bf16x8 af[4], bfr[4];
      const int ko = s * 32 + quad * 8;
#pragma unroll
      for (int mf = 0; mf < 4; ++mf) af[mf]  = *(const bf16x8*)(&As[(wm + mf * 16 + ln) * 72 + ko]);
#pragma unroll
      for (int nf = 0; nf < 4; ++nf) bfr[nf] = *(const bf16x8*)(&Bs[(wn + nf * 16 + ln) * 72 + ko]);
#pragma unroll
      for (int mf = 0; mf < 4; ++mf)
#pragma unroll
        for (int nf = 0; nf < 4; ++nf)
          acc[mf][nf] = __builtin_amdgcn_mfma_f32_16x16x32_bf16(af[mf], bfr[nf], acc[mf][nf], 0, 0, 0);
    }
  }

  // epilogue: D reg r -> row = quad*4+r, col = ln
#pragma unroll
  for (int mf = 0; mf < 4; ++mf) {
#pragma unroll
    for (int r = 0; r < 4; ++r) {
      const int rl = wm + mf * 16 + quad * 4 + r;
      const int gm = m0 + rl;
      if ((MODE == 2 || MODE == 3) && gm >= cnt) continue;
      float wgt = 0.f; int tok = 0;
      if (MODE == 2) wgt = pair_w[segoff + gm];
      if (MODE == 3) tok = pair_token[segoff + gm];
#pragma unroll
      for (int nf = 0; nf < 4; ++nf) {
        const int clg = nt * 128 + wn + nf * 16 + ln;
        const float v = acc[mf][nf][r];
        if (MODE == 0)      Cbf[(long)gm * 2048 + clg] = (__bf16)gelu_f(v);
        else if (MODE == 1) Cf[(long)gm * 2048 + clg] = v;
        else if (MODE == 2) Cbf[(long)(segoff + gm) * 1024 + clg] = (__bf16)(gelu_f(v) * wgt);
        else                atomicAdd(&Cf[(long)tok * 2048 + clg], v);
      }
    }
  }
}

extern "C" void kernel_launch(void* const* d_in, const int* in_sizes, int n_in,
                              void* d_out, int out_size, void* d_ws, size_t ws_size,
                              hipStream_t stream)
{
  (void)in_sizes; (void)n_in; (void)out_size; (void)ws_size;
  const float* x        = (const float*)d_in[0];
  const float* Wsh_up   = (const float*)d_in[1];
  const float* Wsh_down = (const float*)d_in[2];
  const float* Wrt_up   = (const float*)d_in[3];
  const float* Wrt_down = (const float*)d_in[4];
  const float* Wr       = (const float*)d_in[5];
  float* out = (float*)d_out;

  char* w = (char*)d_ws;
  size_t off = 0;
  auto alloc = [&](size_t bytes) -> void* {
    void* p = w + off;
    off = (off + bytes + 255) & ~(size_t)255;
    return p;
  };
  int*    counts  = (int*)alloc(64);     // 16 ints   (ws+0)
  int*    cursor  = (int*)alloc(64);     // 16 ints   (ws+256 after 256B rounding!)
  int*    offsets = (int*)alloc(128);    // 17 ints   (ws+512)
  int*    top_e   = (int*)alloc((size_t)2 * T_TOK * 4);
  float*  top_w   = (float*)alloc((size_t)2 * T_TOK * 4);
  int*    pair_token = (int*)alloc((size_t)NPAIR_PAD * 4);
  float*  pair_w  = (float*)alloc((size_t)NPAIR_PAD * 4);
  bf16_t* xb      = (bf16_t*)alloc((size_t)T_TOK * HDIM * 2);
  bf16_t* xg      = (bf16_t*)alloc((size_t)NPAIR_PAD * HDIM * 2);
  bf16_t* midsh   = (bf16_t*)alloc((size_t)T_TOK * (ESH * DDIM) * 2);
  bf16_t* midrt   = (bf16_t*)alloc((size_t)NPAIR_PAD * DDIM * 2);
  bf16_t* WshUt   = (bf16_t*)alloc((size_t)ESH * DDIM * HDIM * 2);  // [e][D][H]
  bf16_t* WshDt   = (bf16_t*)alloc((size_t)ESH * HDIM * DDIM * 2);  // [e][H][D]
  bf16_t* WrtUt   = (bf16_t*)alloc((size_t)ERT * DDIM * HDIM * 2);  // [e][D][H]
  bf16_t* WrtDt   = (bf16_t*)alloc((size_t)ERT * HDIM * DDIM * 2);  // [e][H][D]
  // total ~236 MB

  // BUGFIX (round 1 crash): alloc() rounds to 256B, so cursor lives at ws+256;
  // the previous 128B memset left cursor poisoned (0xAAAAAAAA) -> scatter_kernel
  // computed wild slots -> device memory fault. Zero the whole small-buffer head.
  hipMemsetAsync(w, 0, 768, stream);  // covers counts, cursor, offsets

  router_kernel<<<T_TOK, 256, 0, stream>>>(x, Wr, top_e, top_w, counts);
  prefix_kernel<<<1, 64, 0, stream>>>(counts, offsets);
  scatter_kernel<<<T_TOK / 256, 256, 0, stream>>>(top_e, top_w, offsets, cursor, pair_token, pair_w);
  cast_x_kernel<<<T_TOK, 256, 0, stream>>>(x, xb);
  gather_kernel<<<NPAIR, 256, 0, stream>>>(x, pair_token, xg);

  // weight transpose+cast: in [R][C] -> out [C][R]
  transpose_cast_kernel<<<dim3(DDIM / 64, HDIM / 64, ESH), 256, 0, stream>>>(Wsh_up,   WshUt, HDIM, DDIM);
  transpose_cast_kernel<<<dim3(HDIM / 64, DDIM / 64, ESH), 256, 0, stream>>>(Wsh_down, WshDt, DDIM, HDIM);
  transpose_cast_kernel<<<dim3(DDIM / 64, HDIM / 64, ERT), 256, 0, stream>>>(Wrt_up,   WrtUt, HDIM, DDIM);
  transpose_cast_kernel<<<dim3(HDIM / 64, DDIM / 64, ERT), 256, 0, stream>>>(Wrt_down, WrtDt, DDIM, HDIM);

  // shared up: [4096,2048] x [2048->2048] -> midsh bf16 [4096][2*1024]
  gemm_kernel<0><<<dim3(32, 16, 1), 256, 0, stream>>>(xb, WshUt, midsh, nullptr,
                                                      nullptr, nullptr, nullptr, nullptr);
  // routed up (grouped): xg segments x Wrt_up_t[e] -> midrt bf16 (gelu * gate)
  gemm_kernel<2><<<dim3(32, 8, ERT), 256, 0, stream>>>(xg, WrtUt, midrt, nullptr,
                                                       counts, offsets, pair_w, nullptr);
  // shared down: midsh x Wsh_down_t (k-segmented) -> out fp32 (overwrites poison)
  gemm_kernel<1><<<dim3(32, 16, 1), 256, 0, stream>>>(midsh, WshDt, nullptr, out,
                                                      nullptr, nullptr, nullptr, nullptr);
  // routed down (grouped): midrt segments x Wrt_down_t[e] -> atomicAdd into out
  gemm_kernel<3><<<dim3(32, 16, ERT), 256, 0, stream>>>(midrt, WrtDt, nullptr, out,
                                                        counts, offsets, nullptr, pair_token);
}

// Round 3
// 1241.059 us; speedup vs baseline: 1.1130x; 1.1130x over previous
//
#include <hip/hip_runtime.h>
#include <cstdint>
#include <cstddef>

typedef __bf16 bf16_t;
typedef __bf16 bf16x8 __attribute__((ext_vector_type(8)));
typedef float floatx4 __attribute__((ext_vector_type(4)));

static constexpr int T_TOK = 4096;
static constexpr int HDIM  = 2048;
static constexpr int DDIM  = 1024;
static constexpr int ESH   = 2;
static constexpr int ERT   = 16;
static constexpr int NPAIR = 2 * T_TOK;         // 8192
static constexpr int NPAIR_PAD = NPAIR + 128;   // pad so tile over-reads stay in-bounds

__device__ __forceinline__ float gelu_f(float v) {
  return 0.5f * v * (1.0f + erff(v * 0.70710678118654752440f));
}

// ---------------- router: logits -> softmax -> top2, atomic counts ----------------
__global__ __launch_bounds__(256) void router_kernel(
    const float* __restrict__ x, const float* __restrict__ Wr,
    int* __restrict__ top_e, float* __restrict__ top_w, int* __restrict__ counts)
{
  const int t = blockIdx.x;
  const int tid = threadIdx.x;
  float acc[ERT];
#pragma unroll
  for (int e = 0; e < ERT; ++e) acc[e] = 0.f;
  const float* xr = x + (long)t * HDIM;
  for (int h = tid; h < HDIM; h += 256) {
    const float xv = xr[h];
    const float4* w4 = (const float4*)(Wr + h * ERT);
    const float4 w0 = w4[0], w1 = w4[1], w2 = w4[2], w3 = w4[3];
    acc[0]  += xv * w0.x; acc[1]  += xv * w0.y; acc[2]  += xv * w0.z; acc[3]  += xv * w0.w;
    acc[4]  += xv * w1.x; acc[5]  += xv * w1.y; acc[6]  += xv * w1.z; acc[7]  += xv * w1.w;
    acc[8]  += xv * w2.x; acc[9]  += xv * w2.y; acc[10] += xv * w2.z; acc[11] += xv * w2.w;
    acc[12] += xv * w3.x; acc[13] += xv * w3.y; acc[14] += xv * w3.z; acc[15] += xv * w3.w;
  }
  __shared__ float s[256][ERT + 1];
#pragma unroll
  for (int e = 0; e < ERT; ++e) s[tid][e] = acc[e];
  __syncthreads();
  for (int st = 128; st >= 1; st >>= 1) {
    if (tid < st) {
#pragma unroll
      for (int e = 0; e < ERT; ++e) s[tid][e] += s[tid + st][e];
    }
    __syncthreads();
  }
  if (tid == 0) {
    float l[ERT];
    float mx = -1e30f;
#pragma unroll
    for (int e = 0; e < ERT; ++e) { l[e] = s[0][e]; mx = fmaxf(mx, l[e]); }
    float sum = 0.f;
#pragma unroll
    for (int e = 0; e < ERT; ++e) { l[e] = expf(l[e] - mx); sum += l[e]; }
    const float inv = 1.f / sum;
    float v0 = -1.f, v1 = -1.f; int i0 = 0, i1 = 0;
#pragma unroll
    for (int e = 0; e < ERT; ++e) {
      const float p = l[e] * inv;
      if (p > v0) { v1 = v0; i1 = i0; v0 = p; i0 = e; }
      else if (p > v1) { v1 = p; i1 = e; }
    }
    top_e[2 * t] = i0; top_e[2 * t + 1] = i1;
    top_w[2 * t] = v0; top_w[2 * t + 1] = v1;
    atomicAdd(&counts[i0], 1); atomicAdd(&counts[i1], 1);
  }
}

// ---------------- tiny prefix sum over 16 experts ----------------
__global__ void prefix_kernel(const int* __restrict__ counts, int* __restrict__ offsets) {
  if (threadIdx.x == 0) {
    int s = 0;
    for (int e = 0; e < ERT; ++e) { offsets[e] = s; s += counts[e]; }
    offsets[ERT] = s;
  }
}

// ---------------- scatter tokens into per-expert contiguous slots ----------------
// Also records inv_slot[2t+k] so the combine kernel can gather pair outputs
// without atomics.
__global__ __launch_bounds__(256) void scatter_kernel(
    const int* __restrict__ top_e, const float* __restrict__ top_w,
    const int* __restrict__ offsets, int* __restrict__ cursor,
    int* __restrict__ pair_token, float* __restrict__ pair_w,
    int* __restrict__ inv_slot)
{
  const int t = blockIdx.x * 256 + threadIdx.x;
  if (t >= T_TOK) return;
#pragma unroll
  for (int k = 0; k < 2; ++k) {
    const int e = top_e[2 * t + k];
    const int pos = atomicAdd(&cursor[e], 1);
    const int slot = offsets[e] + pos;
    pair_token[slot] = t;
    pair_w[slot] = top_w[2 * t + k];
    inv_slot[2 * t + k] = slot;
  }
}

// ---------------- x fp32 -> bf16 ----------------
__global__ __launch_bounds__(256) void cast_x_kernel(const float* __restrict__ x, bf16_t* __restrict__ xb) {
  const long base = (long)blockIdx.x * HDIM + threadIdx.x * 8;
  const float4 a = *(const float4*)(x + base);
  const float4 b = *(const float4*)(x + base + 4);
  bf16x8 v;
  v[0] = (__bf16)a.x; v[1] = (__bf16)a.y; v[2] = (__bf16)a.z; v[3] = (__bf16)a.w;
  v[4] = (__bf16)b.x; v[5] = (__bf16)b.y; v[6] = (__bf16)b.z; v[7] = (__bf16)b.w;
  *(bf16x8*)(xb + base) = v;
}

// ---------------- gather routed rows (fp32 -> bf16) ----------------
__global__ __launch_bounds__(256) void gather_kernel(
    const float* __restrict__ x, const int* __restrict__ pair_token, bf16_t* __restrict__ xg)
{
  const int slot = blockIdx.x;
  const int tok = pair_token[slot];
  const float* src = x + (long)tok * HDIM;
  const int c = threadIdx.x * 8;
  const float4 a = *(const float4*)(src + c);
  const float4 b = *(const float4*)(src + c + 4);
  bf16x8 v;
  v[0] = (__bf16)a.x; v[1] = (__bf16)a.y; v[2] = (__bf16)a.z; v[3] = (__bf16)a.w;
  v[4] = (__bf16)b.x; v[5] = (__bf16)b.y; v[6] = (__bf16)b.z; v[7] = (__bf16)b.w;
  *(bf16x8*)(xg + (long)slot * HDIM + c) = v;
}

// ---------------- transpose + cast: in fp32 [R][C] -> out bf16 [C][R], per mat ----------------
__global__ __launch_bounds__(256) void transpose_cast_kernel(
    const float* __restrict__ in, bf16_t* __restrict__ out, int R, int C)
{
  __shared__ float tl[64][65];
  const long mat = blockIdx.z;
  in  += mat * (long)R * C;
  out += mat * (long)R * C;
  const int c0 = blockIdx.x * 64, r0 = blockIdx.y * 64;
  const int tid = threadIdx.x;
  const int lr = tid >> 4;          // 0..15
  const int lc4 = (tid & 15) * 4;   // 0,4,...,60
#pragma unroll
  for (int i = 0; i < 4; ++i) {
    const int r = lr + i * 16;
    const float4 v = *(const float4*)(in + (long)(r0 + r) * C + c0 + lc4);
    tl[r][lc4 + 0] = v.x; tl[r][lc4 + 1] = v.y; tl[r][lc4 + 2] = v.z; tl[r][lc4 + 3] = v.w;
  }
  __syncthreads();
#pragma unroll
  for (int i = 0; i < 4; ++i) {
    const int c = lr + i * 16;
    ushort4 o;
    o.x = __builtin_bit_cast(unsigned short, (__bf16)tl[lc4 + 0][c]);
    o.y = __builtin_bit_cast(unsigned short, (__bf16)tl[lc4 + 1][c]);
    o.z = __builtin_bit_cast(unsigned short, (__bf16)tl[lc4 + 2][c]);
    o.w = __builtin_bit_cast(unsigned short, (__bf16)tl[lc4 + 3][c]);
    *(ushort4*)((unsigned short*)out + (long)(c0 + c) * R + r0 + lc4) = o;
  }
}

// ---------------- combine: out[t] = sh_out[t] + pair_out[s0] + pair_out[s1] ----------------
__global__ __launch_bounds__(256) void combine_kernel(
    const bf16_t* __restrict__ sh_out, const bf16_t* __restrict__ pair_out,
    const int* __restrict__ inv_slot, float* __restrict__ out)
{
  const int t = blockIdx.x;
  const int c = threadIdx.x * 8;
  const int s0 = inv_slot[2 * t], s1 = inv_slot[2 * t + 1];
  const bf16x8 a = *(const bf16x8*)(sh_out  + (long)t  * HDIM + c);
  const bf16x8 b = *(const bf16x8*)(pair_out + (long)s0 * HDIM + c);
  const bf16x8 d = *(const bf16x8*)(pair_out + (long)s1 * HDIM + c);
  float4 o0, o1;
  o0.x = (float)a[0] + (float)b[0] + (float)d[0];
  o0.y = (float)a[1] + (float)b[1] + (float)d[1];
  o0.z = (float)a[2] + (float)b[2] + (float)d[2];
  o0.w = (float)a[3] + (float)b[3] + (float)d[3];
  o1.x = (float)a[4] + (float)b[4] + (float)d[4];
  o1.y = (float)a[5] + (float)b[5] + (float)d[5];
  o1.z = (float)a[6] + (float)b[6] + (float)d[6];
  o1.w = (float)a[7] + (float)b[7] + (float)d[7];
  *(float4*)(out + (long)t * HDIM + c) = o0;
  *(float4*)(out + (long)t * HDIM + c + 4) = o1;
}

// ---------------- 128x128 MFMA GEMM, BK=64, A:[M][K] bf16, B:[N][K] bf16 (both k-contiguous) --------
// MODE 0: shared-up   C = gelu(A@B^T) -> midsh bf16   (grid 32 x 16)
// MODE 1: shared-down C = A@B^T -> sh_out bf16, B k-segmented per expert (grid 32 x 16)
// MODE 2: routed-up   C = gelu(A@B^T)*w -> midrt bf16, grouped (grid 32 x 8 x 16)
// MODE 3: routed-down C = A@B^T -> pair_out bf16 (per pair row), grouped (grid 32 x 16 x 16)
template<int MODE>
__global__ __launch_bounds__(256) void gemm_kernel(
    const bf16_t* __restrict__ Abase, const bf16_t* __restrict__ Bbase,
    bf16_t* __restrict__ Cbf,
    const int* __restrict__ counts, const int* __restrict__ offsets,
    const float* __restrict__ pair_w)
{
  constexpr int K   = (MODE == 3) ? 1024 : 2048;
  constexpr int LDA = (MODE == 3) ? 1024 : 2048;
  constexpr int LDB = (MODE == 1 || MODE == 3) ? 1024 : 2048;

  const int mt = blockIdx.x, nt = blockIdx.y, e = blockIdx.z;
  const int m0 = mt * 128;
  int cnt = 0, segoff = 0;
  if (MODE == 2 || MODE == 3) {
    cnt = counts[e];
    if (m0 >= cnt) return;
    segoff = offsets[e];
  }

  const bf16_t* Ab;
  const bf16_t* Bb;
  if (MODE == 0) {
    Ab = Abase + (long)m0 * LDA;
    Bb = Bbase + (long)(nt >> 3) * ((long)DDIM * HDIM) + (long)((nt & 7) * 128) * LDB;
  } else if (MODE == 1) {
    Ab = Abase + (long)m0 * LDA;
    Bb = Bbase + (long)(nt * 128) * LDB;
  } else if (MODE == 2) {
    Ab = Abase + (long)(segoff + m0) * LDA;
    Bb = Bbase + (long)e * ((long)DDIM * HDIM) + (long)(nt * 128) * LDB;
  } else {
    Ab = Abase + (long)(segoff + m0) * LDA;
    Bb = Bbase + (long)e * ((long)HDIM * DDIM) + (long)(nt * 128) * LDB;
  }

  __shared__ bf16_t As[128 * 72];   // [m][k], row stride 72 (=9*16B, 16B aligned, conflict-light)
  __shared__ bf16_t Bs[128 * 72];   // [n][k]

  const int tid = threadIdx.x;
  const int rr = tid >> 3, ch = tid & 7;       // staging: row, 16B chunk
  const int lane = tid & 63, wv = tid >> 6;
  const int ln = lane & 15, quad = lane >> 4;
  const int wm = (wv & 1) * 64, wn = (wv >> 1) * 64;

  floatx4 acc[4][4];
#pragma unroll
  for (int i = 0; i < 4; ++i)
#pragma unroll
    for (int j = 0; j < 4; ++j) acc[i][j] = (floatx4){0.f, 0.f, 0.f, 0.f};

  for (int k0 = 0; k0 < K; k0 += 64) {
    bf16x8 av[4], bv[4];
    long bkoff;
    if (MODE == 1) bkoff = (long)(k0 >> 10) * ((long)HDIM * DDIM) + (k0 & 1023);
    else bkoff = k0;
#pragma unroll
    for (int i = 0; i < 4; ++i) {
      av[i] = *(const bf16x8*)(Ab + (long)(rr + i * 32) * LDA + k0 + ch * 8);
      bv[i] = *(const bf16x8*)(Bb + (long)(rr + i * 32) * LDB + bkoff + ch * 8);
    }
    __syncthreads();
#pragma unroll
    for (int i = 0; i < 4; ++i) {
      *(bf16x8*)(&As[(rr + i * 32) * 72 + ch * 8]) = av[i];
      *(bf16x8*)(&Bs[(rr + i * 32) * 72 + ch * 8]) = bv[i];
    }
    __syncthreads();
#pragma unroll
    for (int s = 0; s < 2; ++s) {
      bf16x8 af[4], bfr[4];
      const int ko = s * 32 + quad * 8;
#pragma unroll
      for (int mf = 0; mf < 4; ++mf) af[mf]  = *(const bf16x8*)(&As[(wm + mf * 16 + ln) * 72 + ko]);
#pragma unroll
      for (int nf = 0; nf < 4; ++nf) bfr[nf] = *(const bf16x8*)(&Bs[(wn + nf * 16 + ln) * 72 + ko]);
#pragma unroll
      for (int mf = 0; mf < 4; ++mf)
#pragma unroll
        for (int nf = 0; nf < 4; ++nf)
          acc[mf][nf] = __builtin_amdgcn_mfma_f32_16x16x32_bf16(af[mf], bfr[nf], acc[mf][nf], 0, 0, 0);
    }
  }

  // epilogue: D reg r -> row = quad*4+r, col = ln
#pragma unroll
  for (int mf = 0; mf < 4; ++mf) {
#pragma unroll
    for (int r = 0; r < 4; ++r) {
      const int rl = wm + mf * 16 + quad * 4 + r;
      const int gm = m0 + rl;
      if ((MODE == 2 || MODE == 3) && gm >= cnt) continue;
      float wgt = 0.f;
      if (MODE == 2) wgt = pair_w[segoff + gm];
#pragma unroll
      for (int nf = 0; nf < 4; ++nf) {
        const int clg = nt * 128 + wn + nf * 16 + ln;
        const float v = acc[mf][nf][r];
        if (MODE == 0)      Cbf[(long)gm * 2048 + clg] = (__bf16)gelu_f(v);
        else if (MODE == 1) Cbf[(long)gm * 2048 + clg] = (__bf16)v;
        else if (MODE == 2) Cbf[(long)(segoff + gm) * 1024 + clg] = (__bf16)(gelu_f(v) * wgt);
        else                Cbf[(long)(segoff + gm) * 2048 + clg] = (__bf16)v;
      }
    }
  }
}

extern "C" void kernel_launch(void* const* d_in, const int* in_sizes, int n_in,
                              void* d_out, int out_size, void* d_ws, size_t ws_size,
                              hipStream_t stream)
{
  (void)in_sizes; (void)n_in; (void)out_size; (void)ws_size;
  const float* x        = (const float*)d_in[0];
  const float* Wsh_up   = (const float*)d_in[1];
  const float* Wsh_down = (const float*)d_in[2];
  const float* Wrt_up   = (const float*)d_in[3];
  const float* Wrt_down = (const float*)d_in[4];
  const float* Wr       = (const float*)d_in[5];
  float* out = (float*)d_out;

  char* w = (char*)d_ws;
  size_t off = 0;
  auto alloc = [&](size_t bytes) -> void* {
    void* p = w + off;
    off = (off + bytes + 255) & ~(size_t)255;
    return p;
  };
  int*    counts  = (int*)alloc(64);     // 16 ints   (ws+0)
  int*    cursor  = (int*)alloc(64);     // 16 ints   (ws+256)
  int*    offsets = (int*)alloc(128);    // 17 ints   (ws+512)
  int*    top_e   = (int*)alloc((size_t)2 * T_TOK * 4);
  float*  top_w   = (float*)alloc((size_t)2 * T_TOK * 4);
  int*    pair_token = (int*)alloc((size_t)NPAIR_PAD * 4);
  float*  pair_w  = (float*)alloc((size_t)NPAIR_PAD * 4);
  int*    inv_slot = (int*)alloc((size_t)2 * T_TOK * 4);
  bf16_t* xb      = (bf16_t*)alloc((size_t)T_TOK * HDIM * 2);
  bf16_t* xg      = (bf16_t*)alloc((size_t)NPAIR_PAD * HDIM * 2);
  bf16_t* midsh   = (bf16_t*)alloc((size_t)T_TOK * (ESH * DDIM) * 2);
  bf16_t* midrt   = (bf16_t*)alloc((size_t)NPAIR_PAD * DDIM * 2);
  bf16_t* WshUt   = (bf16_t*)alloc((size_t)ESH * DDIM * HDIM * 2);  // [e][D][H]
  bf16_t* WshDt   = (bf16_t*)alloc((size_t)ESH * HDIM * DDIM * 2);  // [e][H][D]
  bf16_t* WrtUt   = (bf16_t*)alloc((size_t)ERT * DDIM * HDIM * 2);  // [e][D][H]
  bf16_t* WrtDt   = (bf16_t*)alloc((size_t)ERT * HDIM * DDIM * 2);  // [e][H][D]
  // Buffer reuse (stream-serialized, so these aliases are safe):
  //   xb  is dead after gemm<0>  -> reuse as sh_out  (bf16 [T_TOK][HDIM])
  //   xg  is dead after gemm<2>  -> reuse as pair_out (bf16 [NPAIR_PAD][HDIM])
  bf16_t* sh_out   = xb;
  bf16_t* pair_out = xg;

  // Zero the small-buffer head (counts@0, cursor@256, offsets@512).
  hipMemsetAsync(w, 0, 768, stream);

  router_kernel<<<T_TOK, 256, 0, stream>>>(x, Wr, top_e, top_w, counts);
  prefix_kernel<<<1, 64, 0, stream>>>(counts, offsets);
  scatter_kernel<<<T_TOK / 256, 256, 0, stream>>>(top_e, top_w, offsets, cursor,
                                                  pair_token, pair_w, inv_slot);
  cast_x_kernel<<<T_TOK, 256, 0, stream>>>(x, xb);
  gather_kernel<<<NPAIR, 256, 0, stream>>>(x, pair_token, xg);

  // weight transpose+cast: in [R][C] -> out [C][R]
  transpose_cast_kernel<<<dim3(DDIM / 64, HDIM / 64, ESH), 256, 0, stream>>>(Wsh_up,   WshUt, HDIM, DDIM);
  transpose_cast_kernel<<<dim3(HDIM / 64, DDIM / 64, ESH), 256, 0, stream>>>(Wsh_down, WshDt, DDIM, HDIM);
  transpose_cast_kernel<<<dim3(DDIM / 64, HDIM / 64, ERT), 256, 0, stream>>>(Wrt_up,   WrtUt, HDIM, DDIM);
  transpose_cast_kernel<<<dim3(HDIM / 64, DDIM / 64, ERT), 256, 0, stream>>>(Wrt_down, WrtDt, DDIM, HDIM);

  // shared up: xb x WshUt -> midsh bf16 (gelu)
  gemm_kernel<0><<<dim3(32, 16, 1), 256, 0, stream>>>(xb, WshUt, midsh,
                                                      nullptr, nullptr, nullptr);
  // routed up (grouped): xg segments x WrtUt[e] -> midrt bf16 (gelu * gate)
  gemm_kernel<2><<<dim3(32, 8, ERT), 256, 0, stream>>>(xg, WrtUt, midrt,
                                                       counts, offsets, pair_w);
  // shared down: midsh x WshDt (k-segmented) -> sh_out bf16   (sh_out aliases xb: dead after gemm<0>)
  gemm_kernel<1><<<dim3(32, 16, 1), 256, 0, stream>>>(midsh, WshDt, sh_out,
                                                      nullptr, nullptr, nullptr);
  // routed down (grouped): midrt segments x WrtDt[e] -> pair_out bf16 (aliases xg: dead after gemm<2>)
  gemm_kernel<3><<<dim3(32, 16, ERT), 256, 0, stream>>>(midrt, WrtDt, pair_out,
                                                        counts, offsets, nullptr);
  // final combine: out[t] = sh_out[t] + pair_out[slot0(t)] + pair_out[slot1(t)]
  combine_kernel<<<T_TOK, 256, 0, stream>>>(sh_out, pair_out, inv_slot, out);
}